// Round 6
// baseline (530.979 us; speedup 1.0000x reference)
//
#include <hip/hip_runtime.h>
#include <stdint.h>
#include <math.h>

// ---------------------------------------------------------------------------
// GraphDistillOperatorWithEdgeWeight, N=8192, F=256, OUT=256
//
//   E_ij = exp(5*adj_ij), E_ii = 0 ; s_i = sum_j E_ij ; a = E/s
//   agg = a@feat ; kagg = a@key
//   out1 = tanh(Xcat @ W1 + c1),  Xcat=[feat|agg],  W1=[[W_o],[0]] - W_d@W_o
//   out2 = tanh(Kcat @ W2 + c2),  Kcat=[key|kagg],  W2=[[W_ao],[W_a@W_ao]]
//
// Round change (two barrier domains per CU; re-submit of round-5 plan with
// the __exp2f compile error fixed -> __builtin_amdgcn_exp2f):
//  exp_gemm: 4-wave blocks (256 thr), tile 32 rows x 512 cols (wave 32x128),
//  B-ring 2 slots x 8KB/wave in LDS. LDS total 74752 B -> 2 blocks/CU, so one
//  block's MFMA overlaps the other's VALU/barrier (round 4: 1 block/CU,
//  lockstep phases = 6100cy vs ~2100cy of pipe work). vmcnt(10) both waits;
//  refill ordered after slot ds_reads by lgkmcnt(0).
//  finalize_agg adapted to 32-row blobs. grid 1024 / 2048.
// ---------------------------------------------------------------------------

typedef __attribute__((ext_vector_type(4)))  short bf16x4_t;
typedef __attribute__((ext_vector_type(8)))  short bf16x8_t;
typedef __attribute__((ext_vector_type(4)))  float f32x4_t;
typedef __attribute__((ext_vector_type(16))) float f32x16_t;

#define MFMA32(A, B, C) __builtin_amdgcn_mfma_f32_32x32x16_bf16(A, B, C, 0, 0, 0)
#define MFMA16(A, B, C) __builtin_amdgcn_mfma_f32_16x16x32_bf16(A, B, C, 0, 0, 0)

__device__ __forceinline__ unsigned short f2bf(float x) {
    union { float f; unsigned u; } c; c.f = x;
    unsigned u = c.u;
    return (unsigned short)((u + 0x7fffu + ((u >> 16) & 1u)) >> 16);  // RNE
}
__device__ __forceinline__ unsigned pack2bf(float a, float b) {
    return (unsigned)f2bf(a) | ((unsigned)f2bf(b) << 16);
}
__device__ __forceinline__ float bflo(unsigned u) {
    union { unsigned u; float f; } c; c.u = u << 16; return c.f;
}
__device__ __forceinline__ float bfhi(unsigned u) {
    union { unsigned u; float f; } c; c.u = u & 0xffff0000u; return c.f;
}
// exp(5x) = 2^(5*log2(e)*x), single v_exp_f32
__device__ __forceinline__ float exp5(float x) {
    return __builtin_amdgcn_exp2f(7.2134752f * x);
}

// async global->LDS, 16B per lane: LDS dst = uniform base + lane*16
__device__ __forceinline__ void gll16(const unsigned short* g, unsigned short* l) {
    __builtin_amdgcn_global_load_lds(
        (const __attribute__((address_space(1))) unsigned int*)(g),
        (__attribute__((address_space(3))) unsigned int*)(l), 16, 0, 0);
}

// ---------------------------------------------------------------------------
// transpose_blob + fused pack: src[8192][256] f32 -> Xtb fragment blobs AND
// packdst[:, 0:128] bf16-pair halves.
// Blob (j = k/32, c32): 1024 shorts, short idx = s*512 + lane*8 + e, where
// lane = ((k>>3)&1)*32 + (col&31), s = (k>>4)&1, e = k&7.
// grid = (256 k-tiles, 8 col-tiles), block = 256.
// ---------------------------------------------------------------------------
__global__ __launch_bounds__(256) void transpose_blob(
    const float* __restrict__ src, unsigned short* __restrict__ Xtb,
    unsigned* __restrict__ packdst, int c32base)
{
    __shared__ float tile[32][33];
    const int t = threadIdx.x;
    const int x = t & 31, y4 = (t >> 5) * 4;
    const int r0 = blockIdx.x * 32, c0 = blockIdx.y * 32;
#pragma unroll
    for (int i = 0; i < 4; ++i)
        tile[y4 + i][x] = src[(size_t)(r0 + y4 + i) * 256 + c0 + x];
    __syncthreads();
    const int s = t >> 7, lane = (t >> 1) & 63, e0 = (t & 1) * 4;
    const int kl = s * 16 + (lane >> 5) * 8 + e0;   // k-local 0..31
    const int cl = lane & 31;                        // col-local
    unsigned short* blob = Xtb + ((size_t)blockIdx.x * 16 + (c0 >> 5) + c32base) * 1024;
    uint2 v;
    v.x = pack2bf(tile[kl][cl],     tile[kl + 1][cl]);
    v.y = pack2bf(tile[kl + 2][cl], tile[kl + 3][cl]);
    *(uint2*)(blob + t * 4) = v;
    // pack write (XcatN/Kcat cols 0..255 as bf16 pairs)
    const int prow = t >> 3, pc = t & 7;
    unsigned* pd = packdst + (size_t)(r0 + prow) * 256 + (c0 >> 1) + pc * 2;
    pd[0] = pack2bf(tile[prow][pc * 4 + 0], tile[prow][pc * 4 + 1]);
    pd[1] = pack2bf(tile[prow][pc * 4 + 2], tile[prow][pc * 4 + 3]);
}

// ---------------------------------------------------------------------------
// Weight composition, bias fold included (k==512 row computes the c-vector).
// grid = 513.
// ---------------------------------------------------------------------------
__global__ __launch_bounds__(256) void compose1(
    const float* __restrict__ W_d, const float* __restrict__ W_o,
    const float* __restrict__ b_d, const float* __restrict__ b_o,
    unsigned short* __restrict__ W1t, float* __restrict__ c1)
{
    __shared__ float wrow[256];
    const int k = blockIdx.x, t = threadIdx.x;
    const float* srcrow = (k < 512) ? (W_d + (size_t)k * 256) : b_d;
    wrow[t] = srcrow[t];
    __syncthreads();
    float acc = 0.f;
#pragma unroll 8
    for (int m = 0; m < 256; ++m) acc = fmaf(wrow[m], W_o[(size_t)m * 256 + t], acc);
    if (k < 512)
        W1t[(size_t)t * 512 + k] = f2bf((k < 256 ? W_o[(size_t)k * 256 + t] : 0.f) - acc);
    else
        c1[t] = b_o[t] - acc;
}

__global__ __launch_bounds__(256) void compose2(
    const float* __restrict__ W_a, const float* __restrict__ W_ao,
    const float* __restrict__ b_a, const float* __restrict__ b_ao,
    unsigned short* __restrict__ W2t, float* __restrict__ c2)
{
    __shared__ float wrow[256];
    const int k = blockIdx.x, t = threadIdx.x;
    if (k < 256) {
        W2t[(size_t)t * 512 + k] = f2bf(W_ao[(size_t)k * 256 + t]);
        return;
    }
    const float* srcrow = (k < 512) ? (W_a + (size_t)(k - 256) * 256) : b_a;
    wrow[t] = srcrow[t];
    __syncthreads();
    float acc = 0.f;
#pragma unroll 8
    for (int m = 0; m < 256; ++m) acc = fmaf(wrow[m], W_ao[(size_t)m * 256 + t], acc);
    if (k < 512) W2t[(size_t)t * 512 + k] = f2bf(acc);
    else         c2[t] = b_ao[t] + acc;
}

// ---------------------------------------------------------------------------
// exp_gemm: Upart[h] = bf16( E_slice @ [feat|key] ), rowsum partials f32.
// grid = 1024 (256 rowblocks x 4 K-split), block = 256 (4 waves).
// Block tile: 32 rows x 512 cols, K-slice 2048. Wave: 32 rows x 128 cols
// (4 ct of 32x32). LDS 74752 B -> 2 blocks/CU (2 barrier domains).
// 32 phases of 2 k-steps; B-ring 2 slots/wave in LDS, vmcnt(10) waits.
// ---------------------------------------------------------------------------
#define ROWS 32
#define KSLICE 2048
#define NPH 32      // phases of 2 k-steps
#define ASTRIDE 36  // padded LDS row stride (shorts)

struct QA { float4 v[2]; };

__global__ __launch_bounds__(256, 2) void exp_gemm(
    const float* __restrict__ adj, const unsigned short* __restrict__ Xtb,
    unsigned* __restrict__ UpartB, float* __restrict__ sSp)
{
    __shared__ unsigned short sA[2][2][ROWS * ASTRIDE];  // 9216 B
    __shared__ unsigned short sB[4][2][4096];            // 65536 B (B ring)

    const int t = threadIdx.x;
    const int w = t >> 6, lane = t & 63, q = lane >> 5, l31 = lane & 31;
    // XCD-affine decode: each XCD owns ONE h-slice (2MB Xtb hot in its L2)
    const int xcd = blockIdx.x & 7;
    const int h = xcd >> 1;
    const int rb = ((blockIdx.x >> 3) << 1) | (xcd & 1);   // 0..255
    const int row0 = rb * ROWS;
    const int kbase = h * KSLICE, jbase = h * (KSLICE / 32);

    // stager role: row srow (t>>3, 0..31), k-offset skoff (8 threads/row)
    const int srow = t >> 3, skoff = (t & 7) * 4;
    const int sgrow = row0 + srow;
    const float* adj_row = adj + (size_t)sgrow * 8192 + kbase + skoff;
    const int swoff = srow * ASTRIDE + skoff;

    // wave w owns cols w*128..w*128+127 (c32 = 4w..4w+3); 8KB contiguous per j
    const unsigned short* XtbW = Xtb + (size_t)jbase * 16384 + (size_t)w * 4096 + lane * 8;
    unsigned short* const sBw = &sB[w][0][0];

    float rs = 0.f;
    f32x16_t acc[4];
#pragma unroll
    for (int ct = 0; ct < 4; ++ct)
#pragma unroll
        for (int e = 0; e < 16; ++e) acc[ct][e] = 0.f;

    QA qa0, qa1, qa2, qa3;  // adj 4-deep prefetch

    auto loadAdj = [&](int cidx, QA& qq) {
        qq.v[0] = *(const float4*)(adj_row + (size_t)(cidx * 2 + 0) * 32);
        qq.v[1] = *(const float4*)(adj_row + (size_t)(cidx * 2 + 1) * 32);
    };

    auto stageChunk = [&](int cidx, const QA& qq, int buf) {
#pragma unroll
        for (int ks = 0; ks < 2; ++ks) {
            const float4 v = qq.v[ks];
            float e0 = exp5(v.x);
            float e1 = exp5(v.y);
            float e2 = exp5(v.z);
            float e3 = exp5(v.w);
            const int gk = kbase + (cidx * 2 + ks) * 32 + skoff;
            if (gk + 0 == sgrow) e0 = 0.f;   // diagonal mask
            if (gk + 1 == sgrow) e1 = 0.f;
            if (gk + 2 == sgrow) e2 = 0.f;
            if (gk + 3 == sgrow) e3 = 0.f;
            rs += (e0 + e1) + (e2 + e3);
            uint2 p; p.x = pack2bf(e0, e1); p.y = pack2bf(e2, e3);
            *(uint2*)(&sA[buf][ks][swoff]) = p;
        }
    };

    auto issueB = [&](int jn, int slot) {  // 8 vm ops, 8KB into ring slot
        const unsigned short* src = XtbW + (size_t)jn * 16384;
        unsigned short* dst = sBw + slot * 4096;
#pragma unroll
        for (int k4 = 0; k4 < 8; ++k4)
            gll16(src + k4 * 512, dst + k4 * 512);
    };

    // read slot u, then refill it with j=jnext (ordered by lgkmcnt(0)), MFMA
    auto consume = [&](int buf, int u, int jnext) {
        const unsigned short* sbp = sBw + u * 4096 + lane * 8;
        bf16x8_t bfr[4][2];
#pragma unroll
        for (int ct = 0; ct < 4; ++ct)
#pragma unroll
            for (int s = 0; s < 2; ++s)
                bfr[ct][s] = *(const bf16x8_t*)(sbp + ct * 1024 + s * 512);
        const unsigned short* sa = &sA[buf][u][0] + l31 * ASTRIDE + q * 8;
        bf16x8_t af[2];
#pragma unroll
        for (int s = 0; s < 2; ++s) {
            const unsigned short* p = sa + s * 16;
            bf16x4_t lo = *(const bf16x4_t*)p;
            bf16x4_t hi = *(const bf16x4_t*)(p + 4);
            af[s] = __builtin_shufflevector(lo, hi, 0, 1, 2, 3, 4, 5, 6, 7);
        }
        asm volatile("s_waitcnt lgkmcnt(0)" ::: "memory");  // reads done before refill
        issueB(jnext, u);
        __builtin_amdgcn_s_setprio(1);
#pragma unroll
        for (int s = 0; s < 2; ++s)
#pragma unroll
            for (int ct = 0; ct < 4; ++ct)
                acc[ct] = MFMA32(af[s], bfr[ct][s], acc[ct]);
        __builtin_amdgcn_s_setprio(0);
    };

    // Phase c (buf = c&1): stage chunk c+1; consume j0=2c (slot0), j1 (slot1),
    // refilling each slot with j+2. Steady state both waits = vmcnt(10):
    // younger-than-j0 = j1 fills (8) + adj (2); younger-than-j1 = adj (2) +
    // j0-refill (8). adj (chunk c+4) issued at phase END.
    auto phase = [&](int c, const QA& qstg, QA& qld, int buf) {
        if (c + 1 < NPH) stageChunk(c + 1, qstg, buf ^ 1);
        asm volatile("s_waitcnt vmcnt(10)" ::: "memory");
        consume(buf, 0, (2 * c + 2) & 63);
        asm volatile("s_waitcnt vmcnt(10)" ::: "memory");
        consume(buf, 1, (2 * c + 3) & 63);
        loadAdj((c + 4) & 31, qld);
        // lgkm-only barrier: sA handoff; global-load queue stays in flight
        asm volatile("s_waitcnt lgkmcnt(0)\n\ts_barrier" ::: "memory");
    };

    // prologue: B j=0,1 -> slots 0,1; adj chunks 0..3; stage chunk 0.
    issueB(0, 0); issueB(1, 1);
    loadAdj(0, qa0); loadAdj(1, qa1); loadAdj(2, qa2); loadAdj(3, qa3);
    stageChunk(0, qa0, 0);
    asm volatile("s_waitcnt lgkmcnt(0)\n\ts_barrier" ::: "memory");

    for (int c0 = 0; c0 < NPH; c0 += 4) {
        phase(c0 + 0, qa1, qa0, 0);
        phase(c0 + 1, qa2, qa1, 1);
        phase(c0 + 2, qa3, qa2, 0);
        phase(c0 + 3, qa0, qa3, 1);
    }

    // rowsum partial: 8 stager threads per row
    rs += __shfl_xor(rs, 1);
    rs += __shfl_xor(rs, 2);
    rs += __shfl_xor(rs, 4);
    if ((t & 7) == 0) sSp[h * 8192 + sgrow] = rs;

    // blocked store: per-(wave,colpair) 4KB blob (32 rows x 64 cols).
    // uint idx = (c2*8+ip)*64 + lane holds rows rlo/rlo+1 where
    // rlo = 2*(ip&1) + 8*(ip>>1) + 4*q, col = c2*32 + (lane&31).
    unsigned* upBase = UpartB + (((size_t)h * 256 + rb) * 8 + w * 2) * 1024 + lane;
#pragma unroll
    for (int cp = 0; cp < 2; ++cp)
#pragma unroll
        for (int c2 = 0; c2 < 2; ++c2)
#pragma unroll
            for (int ip = 0; ip < 8; ++ip)
                upBase[(size_t)cp * 1024 + (c2 * 8 + ip) * 64] =
                    pack2bf(acc[cp * 2 + c2][2 * ip], acc[cp * 2 + c2][2 * ip + 1]);
}

// ---------------------------------------------------------------------------
// finalize: sum 4 blocked bf16 partials, normalize; agg -> XcatN[:,256:512],
// kagg -> Kcat[:,256:512]. Blobs are 32 rows x 64 cols (1024 uints).
// grid = 2048 (256 rowblocks-of-32 x 8 col-groups-of-64), block = 256.
// ---------------------------------------------------------------------------
__global__ __launch_bounds__(256) void finalize_agg(
    const unsigned* __restrict__ UpartB, const float* __restrict__ sSp,
    unsigned* __restrict__ XcatN, unsigned* __restrict__ Kcat)
{
    __shared__ float sT[32][65];
    __shared__ float sInv[32];

    const int t = threadIdx.x;
    const int rb = blockIdx.x >> 3, wp = blockIdx.x & 7;
    const int row0 = rb * 32;

    if (t < 32) {
        const int r = row0 + t;
        sInv[t] = 1.f / (sSp[r] + sSp[8192 + r] + sSp[16384 + r] + sSp[24576 + r]);
    }

    // decode: thread t covers uint index i = t>>4, lanes l0..l0+3
    const int i = t >> 4;                 // 0..15
    const int l0 = (t & 15) * 4;          // 0..60
    const int ct2 = i >> 3, ip = i & 7;
    const int qq = l0 >> 5;
    const int rlo = 2 * (ip & 1) + 8 * (ip >> 1) + 4 * qq;
    const int cbase = ct2 * 32 + (l0 & 31);

    float lo[4], hi[4];
#pragma unroll
    for (int j = 0; j < 4; ++j) { lo[j] = 0.f; hi[j] = 0.f; }
#pragma unroll
    for (int h = 0; h < 4; ++h) {
        const unsigned* src = UpartB + (((size_t)h * 256 + rb) * 8 + wp) * 1024
                              + (size_t)i * 64 + l0;
        const uint4 v0 = *(const uint4*)(src);
        const unsigned vv[4] = { v0.x, v0.y, v0.z, v0.w };
#pragma unroll
        for (int j = 0; j < 4; ++j) { lo[j] += bflo(vv[j]); hi[j] += bfhi(vv[j]); }
    }
#pragma unroll
    for (int j = 0; j < 4; ++j) {
        sT[rlo][cbase + j]     = lo[j];
        sT[rlo + 1][cbase + j] = hi[j];
    }
    __syncthreads();

    // write: thread -> row = t>>3 (0..31), 8 f32 cols at (t&7)*8
    const int row = t >> 3, cg = (t & 7) * 8;
    const float inv = sInv[row];
    unsigned outv[4];
#pragma unroll
    for (int j = 0; j < 4; ++j)
        outv[j] = pack2bf(sT[row][cg + 2 * j] * inv, sT[row][cg + 2 * j + 1] * inv);
    unsigned* dst = (wp < 4 ? XcatN : Kcat)
                    + (size_t)(row0 + row) * 256 + 128 + (wp & 3) * 32 + (cg >> 1);
    *(uint4*)(dst) = *(const uint4*)(outv);
}

// ---------------------------------------------------------------------------
// gemm_out (fused both problems): out[8192][256] f32 =
//   tanh(A[8192][512]bf16 @ Wt[256][512]^T + c).
// grid = 512 (2 problems x 256 Mtiles of 32), block = 256 (4 waves).
// ---------------------------------------------------------------------------
__global__ __launch_bounds__(256) void gemm_out(
    const unsigned short* __restrict__ Aa, const unsigned short* __restrict__ Wta,
    const float* __restrict__ ca,
    const unsigned short* __restrict__ Ab, const unsigned short* __restrict__ Wtb,
    const float* __restrict__ cb,
    float* __restrict__ outa, float* __restrict__ outb)
{
    __shared__ unsigned short sAm[32 * ASTRIDE];
    __shared__ unsigned short sB[256 * ASTRIDE];
    __shared__ float sBias[256];

    const int bid = blockIdx.x;
    const int prob = bid >> 8, tile = bid & 255;
    const unsigned short* A  = prob ? Ab  : Aa;
    const unsigned short* Wt = prob ? Wtb : Wta;
    const float* cvec        = prob ? cb  : ca;
    float* out               = prob ? outb : outa;

    const int t = threadIdx.x, w = t >> 6, lane = t & 63;
    const int m_lo = lane & 15, quad = lane >> 4;
    const int row0 = tile * 32;
    sBias[t] = cvec[t];

    f32x4_t acc[2][4];
#pragma unroll
    for (int a = 0; a < 2; ++a)
#pragma unroll
        for (int b = 0; b < 4; ++b)
#pragma unroll
            for (int e = 0; e < 4; ++e) acc[a][b][e] = 0.f;

    for (int ks = 0; ks < 16; ++ks) {
        const int k0 = ks * 32;
        __syncthreads();
        if (t < 128) {  // A tile 32x32
            bf16x8_t v = *(const bf16x8_t*)(A + (size_t)(row0 + (t >> 2)) * 512 + k0 + (t & 3) * 8);
            unsigned short* d = &sAm[(t >> 2) * ASTRIDE + (t & 3) * 8];
            *(bf16x4_t*)d       = __builtin_shufflevector(v, v, 0, 1, 2, 3);
            *(bf16x4_t*)(d + 4) = __builtin_shufflevector(v, v, 4, 5, 6, 7);
        }
        {               // B tile 256x32, thread t stages n-row t
            const unsigned short* src = Wt + (size_t)t * 512 + k0;
            unsigned short* d = &sB[t * ASTRIDE];
#pragma unroll
            for (int j = 0; j < 4; ++j) {
                bf16x8_t v = *(const bf16x8_t*)(src + j * 8);
                *(bf16x4_t*)(d + j * 8)     = __builtin_shufflevector(v, v, 0, 1, 2, 3);
                *(bf16x4_t*)(d + j * 8 + 4) = __builtin_shufflevector(v, v, 4, 5, 6, 7);
            }
        }
        __syncthreads();
        bf16x8_t a0, a1;
        {
            const unsigned short* p = &sAm[m_lo * ASTRIDE + quad * 8];
            bf16x4_t lo = *(const bf16x4_t*)p, hi = *(const bf16x4_t*)(p + 4);
            a0 = __builtin_shufflevector(lo, hi, 0, 1, 2, 3, 4, 5, 6, 7);
            p += 16 * ASTRIDE;
            lo = *(const bf16x4_t*)p; hi = *(const bf16x4_t*)(p + 4);
            a1 = __builtin_shufflevector(lo, hi, 0, 1, 2, 3, 4, 5, 6, 7);
        }
#pragma unroll
        for (int nt = 0; nt < 4; ++nt) {
            const unsigned short* p = &sB[(w * 64 + nt * 16 + m_lo) * ASTRIDE + quad * 8];
            bf16x4_t lo = *(const bf16x4_t*)p, hi = *(const bf16x4_t*)(p + 4);
            bf16x8_t b = __builtin_shufflevector(lo, hi, 0, 1, 2, 3, 4, 5, 6, 7);
            acc[0][nt] = MFMA16(a0, b, acc[0][nt]);
            acc[1][nt] = MFMA16(a1, b, acc[1][nt]);
        }
    }

#pragma unroll
    for (int mt = 0; mt < 2; ++mt)
#pragma unroll
        for (int nt = 0; nt < 4; ++nt) {
            const int col = w * 64 + nt * 16 + m_lo;
#pragma unroll
            for (int r = 0; r < 4; ++r) {
                const int row = row0 + mt * 16 + quad * 4 + r;
                out[(size_t)row * 256 + col] = tanhf(acc[mt][nt][r] + sBias[col]);
            }
        }
}

// ---------------------------------------------------------------------------
extern "C" void kernel_launch(void* const* d_in, const int* in_sizes, int n_in,
                              void* d_out, int out_size, void* d_ws, size_t ws_size,
                              hipStream_t stream) {
    const float* features = (const float*)d_in[0];
    const float* key      = (const float*)d_in[1];
    const float* adj      = (const float*)d_in[2];
    const float* W_d  = (const float*)d_in[3];
    const float* b_d  = (const float*)d_in[4];
    const float* W_o  = (const float*)d_in[5];
    const float* b_o  = (const float*)d_in[6];
    const float* W_a  = (const float*)d_in[7];
    const float* b_a  = (const float*)d_in[8];
    const float* W_ao = (const float*)d_in[9];
    const float* b_ao = (const float*)d_in[10];

    float* out1 = (float*)d_out;
    float* out2 = out1 + (size_t)8192 * 256;

    char* ws = (char*)d_ws;
    unsigned short* XcatN = (unsigned short*)(ws);                 // [8192][512] bf16, 8 MB
    unsigned short* Kcat  = (unsigned short*)(ws +  8388608);      // [8192][512] bf16, 8 MB
    unsigned short* Xtb   = (unsigned short*)(ws + 16777216);      // fragment blobs, 8 MB
    unsigned*       UpartB= (unsigned*)      (ws + 25165824);      // blocked [4][256][8][1024] u32, 32 MB
    float*          sSp   = (float*)         (ws + 58720256);      // [4][8192] f32
    unsigned short* W1t   = (unsigned short*)(ws + 58851328);      // [256][512] bf16
    unsigned short* W2t   = (unsigned short*)(ws + 59113472);      // [256][512] bf16
    float*          c1    = (float*)         (ws + 59375616);      // [256]
    float*          c2    = (float*)         (ws + 59376640);      // [256]

    dim3 blk(256);
    transpose_blob<<<dim3(256, 8), blk, 0, stream>>>(features, Xtb, (unsigned*)XcatN, 0);
    transpose_blob<<<dim3(256, 8), blk, 0, stream>>>(key, Xtb, (unsigned*)Kcat, 8);
    compose1<<<513, blk, 0, stream>>>(W_d, W_o, b_d, b_o, W1t, c1);
    compose2<<<513, blk, 0, stream>>>(W_a, W_ao, b_a, b_ao, W2t, c2);

    exp_gemm<<<1024, blk, 0, stream>>>(adj, Xtb, UpartB, sSp);
    finalize_agg<<<2048, blk, 0, stream>>>(UpartB, sSp,
                                           (unsigned*)XcatN, (unsigned*)Kcat);

    gemm_out<<<512, blk, 0, stream>>>(XcatN, W1t, c1, Kcat, W2t, c2, out1, out2);
}